// Round 4
// baseline (475.721 us; speedup 1.0000x reference)
//
#include <hip/hip_runtime.h>
#include <hip/hip_bf16.h>

// Problem sizes (fixed)
#define B_SZ 131072
#define F_SZ 784
#define H_SZ 392
#define D_SZ 28
#define K_SZ 512
#define HSTR 424   // hs row stride in shorts (>=416, multiple of 8)

typedef __attribute__((ext_vector_type(8))) short short8v;
typedef __attribute__((ext_vector_type(4))) float f32x4;

__device__ inline short f2bf(float f) {
  __hip_bfloat16 h = __float2bfloat16(f);
  return __builtin_bit_cast(short, h);
}

__device__ inline int swz4(int r) { return (r & 3) ^ ((r >> 2) & 3); }

// ws layout (float offsets)
#define WS_PN2   401408
#define WS_P1    532992
#define WS_PR    535040
#define WS_W1T   537088
#define WS_W2T   716288
#define WS_M2P   722944

// ---------------------------------------------------------------------------
// Decoder table: x_rec_table[k] = relu(prior[k]@W3+b3)@W4 + b4 ; pn2[k]
// ---------------------------------------------------------------------------
__global__ __launch_bounds__(256) void precompute_kernel(
    const float* __restrict__ W3, const float* __restrict__ b3,
    const float* __restrict__ W4, const float* __restrict__ b4,
    const float* __restrict__ prior,
    float* __restrict__ table, float* __restrict__ pn2) {
  __shared__ float ps[D_SZ];
  __shared__ float h2s[H_SZ];
  const int k = blockIdx.x;
  const int t = threadIdx.x;
  if (t < D_SZ) ps[t] = prior[k * D_SZ + t];
  __syncthreads();
  for (int j = t; j < H_SZ; j += 256) {
    float acc = b3[j];
    #pragma unroll
    for (int d = 0; d < D_SZ; ++d) acc += ps[d] * W3[d * H_SZ + j];
    h2s[j] = fmaxf(acc, 0.f);
  }
  if (t == 0) {
    float s = 0.f;
    #pragma unroll
    for (int d = 0; d < D_SZ; ++d) s += ps[d] * ps[d];
    pn2[k] = s;
  }
  __syncthreads();
  for (int f = t; f < F_SZ; f += 256) {
    float acc = b4[f];
    for (int j = 0; j < H_SZ; ++j) acc += h2s[j] * W4[j * F_SZ + f];
    table[(size_t)k * F_SZ + f] = acc;
  }
}

// ---------------------------------------------------------------------------
// W1T[c][k] = bf16(W1[k][c]), [448][800], zero-padded. LDS-tiled transpose.
// ---------------------------------------------------------------------------
__global__ __launch_bounds__(256) void w1t_kernel(const float* __restrict__ W1,
                                                  short* __restrict__ W1T) {
  __shared__ float tile[64][65];
  const int k0 = blockIdx.x * 64;
  const int c0 = blockIdx.y * 64;
  const int t = threadIdx.x;
  for (int i = t; i < 4096; i += 256) {
    const int kk = i >> 6, cc = i & 63;
    const int k = k0 + kk, c = c0 + cc;
    tile[kk][cc] = (k < F_SZ && c < H_SZ) ? W1[(size_t)k * H_SZ + c] : 0.f;
  }
  __syncthreads();
  for (int i = t; i < 4096; i += 256) {
    const int cc = i >> 6, kk = i & 63;
    const int k = k0 + kk, c = c0 + cc;
    if (k < 800) W1T[(size_t)c * 800 + k] = f2bf(tile[kk][cc]);
  }
}

// ---------------------------------------------------------------------------
// W2T[d][j] = bf16(W2[j][d]) [32][416] ; M2P[c][d] = bf16(-2*prior[c][d]) [512][32]
// ---------------------------------------------------------------------------
__global__ __launch_bounds__(256) void prep2_kernel(
    const float* __restrict__ W2, const float* __restrict__ prior,
    short* __restrict__ W2T, short* __restrict__ M2P) {
  const int i = blockIdx.x * 256 + threadIdx.x;
  if (i < 32 * 416) {
    const int d = i / 416, j = i % 416;
    W2T[i] = f2bf((d < D_SZ && j < H_SZ) ? W2[(size_t)j * D_SZ + d] : 0.f);
  }
  if (i < K_SZ * 32) {
    const int c = i / 32, dd = i % 32;
    M2P[i] = f2bf((dd < D_SZ) ? -2.f * prior[(size_t)c * D_SZ + dd] : 0.f);
  }
}

// ---------------------------------------------------------------------------
// Fused encoder v4: barrier-free main loop, fragments direct from global.
//   GEMM1: h = relu(X@W1+b1), acc in regs (64 rows x 448 cols per block,
//          4 waves N-split, A/B fragments loaded straight from HBM/L2).
//   Phase 2 (two 32-row halves through small hs LDS): z = h@W2+b2.
//   Phase 3: distances via MFMA, argmin; loss1 = min distance.
//   Fused loss_rec: Sum ||x - table[idx]||^2.
// LDS ~34KB -> 3-4 blocks/CU; launch_bounds(256,3) caps VGPR at 170.
// ---------------------------------------------------------------------------
__global__ __launch_bounds__(256, 3) void encoder_kernel(
    const float* __restrict__ X, const short* __restrict__ W1T,
    const float* __restrict__ b1, const short* __restrict__ W2T,
    const float* __restrict__ b2, const short* __restrict__ M2P,
    const float* __restrict__ pn2, const float* __restrict__ table,
    float* __restrict__ partial1, float* __restrict__ partialR) {
  __shared__ short hs[32][HSTR];    // 27,136 B (one 32-row half of h)
  __shared__ short zs[64][32];      // 4,096 B (bf16 z, granule-swizzled)
  __shared__ float pn2s[K_SZ];      // 2,048 B
  __shared__ float zn2p[2][64];     // 512 B (zn2 partials per d-half)
  __shared__ float red1[4], redR[4];

  const int t = threadIdx.x;
  const int w = t >> 6;       // wave 0..3 (N-split in GEMM1)
  const int l = t & 63;
  const int lr = l & 15;
  const int lk = (l >> 4) * 8;
  const int row0 = blockIdx.x * 64;

  f32x4 acc[4][7];
  #pragma unroll
  for (int mt = 0; mt < 4; ++mt)
    #pragma unroll
    for (int nt = 0; nt < 7; ++nt) acc[mt][nt] = (f32x4){0.f, 0.f, 0.f, 0.f};

  float b1v[7];
  #pragma unroll
  for (int nt = 0; nt < 7; ++nt) {
    const int c = w * 112 + nt * 16 + lr;
    b1v[nt] = (c < H_SZ) ? b1[c] : 0.f;
  }
  for (int i = t; i < K_SZ; i += 256) pn2s[i] = pn2[i];

  // ---- GEMM1 main loop: 25 K-steps of 32, no LDS, no barriers ----
  const short* wb = W1T + (size_t)(w * 112 + lr) * 800 + lk;
  const float* xb = X + (size_t)(row0 + lr) * F_SZ + lk;
  for (int ks = 0; ks < 25; ++ks) {
    const int kc = ks * 32 + lk;
    short8v afr[4];
    #pragma unroll
    for (int mt = 0; mt < 4; ++mt) {
      float4 xa = {0.f, 0.f, 0.f, 0.f}, xc = {0.f, 0.f, 0.f, 0.f};
      if (kc < F_SZ) {
        const float* xp = xb + (size_t)mt * (16 * F_SZ) + ks * 32;
        xa = *(const float4*)xp;
        xc = *(const float4*)(xp + 4);
      }
      short8v a;
      a[0] = f2bf(xa.x); a[1] = f2bf(xa.y); a[2] = f2bf(xa.z); a[3] = f2bf(xa.w);
      a[4] = f2bf(xc.x); a[5] = f2bf(xc.y); a[6] = f2bf(xc.z); a[7] = f2bf(xc.w);
      afr[mt] = a;
    }
    #pragma unroll
    for (int nt = 0; nt < 7; ++nt) {
      const short8v bfr = *(const short8v*)(wb + (size_t)nt * (16 * 800) + ks * 32);
      #pragma unroll
      for (int mt = 0; mt < 4; ++mt)
        acc[mt][nt] = __builtin_amdgcn_mfma_f32_16x16x32_bf16(afr[mt], bfr, acc[mt][nt], 0, 0, 0);
    }
  }

  // ---- phase 2 in two 32-row halves: hs -> z = h@W2 + b2 ----
  f32x4 zaH[2];   // z C-frag per half (kept for nothing beyond the half loop)
  for (int hf = 0; hf < 2; ++hf) {
    // write this half's h (bias+relu, bf16) to hs
    #pragma unroll
    for (int mtl = 0; mtl < 2; ++mtl) {
      const int mt = 2 * hf + mtl;
      #pragma unroll
      for (int nt = 0; nt < 7; ++nt) {
        const int c = w * 112 + nt * 16 + lr;
        if (c < 416) {
          #pragma unroll
          for (int rg = 0; rg < 4; ++rg) {
            const int rL = mtl * 16 + 4 * (l >> 4) + rg;
            hs[rL][c] = f2bf(fmaxf(acc[mt][nt][rg] + b1v[nt], 0.f));
          }
        }
      }
    }
    __syncthreads();
    // z-GEMM: wave handles rows (w>>1)*16.. and d-half (w&1)
    const int rL = (w >> 1) * 16 + lr;
    const int cD = (w & 1) * 16 + lr;
    const float b2v = (cD < D_SZ) ? b2[cD] : 0.f;
    f32x4 za = (f32x4){b2v, b2v, b2v, b2v};
    #pragma unroll
    for (int ks2 = 0; ks2 < 13; ++ks2) {
      const int u = 4 * ks2 + (l >> 4);
      const short8v af = *(const short8v*)&hs[rL][u * 8];
      const short8v bf = *(const short8v*)&W2T[cD * 416 + ks2 * 32 + lk];
      za = __builtin_amdgcn_mfma_f32_16x16x32_bf16(af, bf, za, 0, 0, 0);
    }
    // zn2 partials (f32) + z writes (bf16, phase-3 layout)
    #pragma unroll
    for (int rg = 0; rg < 4; ++rg) {
      float s = za[rg] * za[rg];
      s += __shfl_xor(s, 1); s += __shfl_xor(s, 2);
      s += __shfl_xor(s, 4); s += __shfl_xor(s, 8);
      const int row = 32 * hf + (w >> 1) * 16 + 4 * (l >> 4) + rg;
      if (lr == 0) zn2p[w & 1][row] = s;
      const int sg = (cD >> 3) ^ swz4(row);
      zs[row][sg * 8 + (cD & 7)] = f2bf(za[rg]);
    }
    zaH[hf] = za;
    __syncthreads();   // protects hs overwrite (hf=0) / publishes zs,zn2p (hf=1)
  }
  asm volatile("" :: "v"(zaH[0][0]), "v"(zaH[1][0]));  // keepalive (no-op)

  // ---- phase 3: d = ||z||^2 - 2 z.p + ||p||^2 via MFMA, argmin ----
  const int rowA = w * 16 + lr;
  const int gA = (l >> 4) ^ swz4(rowA);
  const short8v zf = *(const short8v*)&zs[rowA][gA * 8];
  float zn2r[4];
  #pragma unroll
  for (int rg = 0; rg < 4; ++rg) {
    const int row = w * 16 + 4 * (l >> 4) + rg;
    zn2r[rg] = zn2p[0][row] + zn2p[1][row];
  }
  float bv[4] = {3.4e38f, 3.4e38f, 3.4e38f, 3.4e38f};
  int bi[4] = {0, 0, 0, 0};
  #pragma unroll 8
  for (int nt = 0; nt < 32; ++nt) {
    const int code = nt * 16 + lr;
    const short8v pf = *(const short8v*)&M2P[code * 32 + lk];
    f32x4 dacc = (f32x4){zn2r[0], zn2r[1], zn2r[2], zn2r[3]};
    dacc = __builtin_amdgcn_mfma_f32_16x16x32_bf16(zf, pf, dacc, 0, 0, 0);
    const float pn = pn2s[code];
    #pragma unroll
    for (int rg = 0; rg < 4; ++rg) {
      const float dv = fmaxf(dacc[rg] + pn, 0.f);
      if (dv < bv[rg]) { bv[rg] = dv; bi[rg] = code; }  // ascending: first-min
    }
  }
  #pragma unroll
  for (int rg = 0; rg < 4; ++rg) {
    float v = bv[rg]; int ii = bi[rg];
    #pragma unroll
    for (int m = 1; m <= 8; m <<= 1) {
      const float ov = __shfl_xor(v, m);
      const int oi = __shfl_xor(ii, m);
      if (ov < v || (ov == v && oi < ii)) { v = ov; ii = oi; }
    }
    bv[rg] = v; bi[rg] = ii;
  }

  // loss_1 partial: min distance itself (16 lanes/group hold duplicates -> gate)
  float lsum = (lr == 0) ? (bv[0] + bv[1] + bv[2] + bv[3]) : 0.f;

  // ---- fused loss_rec: this wave's 16 rows, Sum ||x - table[idx]||^2 ----
  float racc = 0.f;
  #pragma unroll 4
  for (int rr = 0; rr < 16; ++rr) {
    const int kk = __shfl(bi[rr & 3], (rr >> 2) << 4);
    const float4* xr4 = (const float4*)&X[(size_t)(row0 + w * 16 + rr) * F_SZ];
    const float4* tr4 = (const float4*)&table[(size_t)kk * F_SZ];
    #pragma unroll
    for (int s = 0; s < 3; ++s) {
      const int i = l + 64 * s;
      const float4 xv = xr4[i], tv = tr4[i];
      const float d0 = xv.x - tv.x, d1 = xv.y - tv.y, d2 = xv.z - tv.z, d3 = xv.w - tv.w;
      racc += d0 * d0 + d1 * d1 + d2 * d2 + d3 * d3;
    }
    if (l < 4) {
      const int i = 192 + l;
      const float4 xv = xr4[i], tv = tr4[i];
      const float d0 = xv.x - tv.x, d1 = xv.y - tv.y, d2 = xv.z - tv.z, d3 = xv.w - tv.w;
      racc += d0 * d0 + d1 * d1 + d2 * d2 + d3 * d3;
    }
  }

  // ---- block reduction ----
  #pragma unroll
  for (int m = 1; m <= 32; m <<= 1) {
    lsum += __shfl_xor(lsum, m);
    racc += __shfl_xor(racc, m);
  }
  if (l == 0) { red1[w] = lsum; redR[w] = racc; }
  __syncthreads();
  if (t == 0) {
    partial1[blockIdx.x] = red1[0] + red1[1] + red1[2] + red1[3];
    partialR[blockIdx.x] = redR[0] + redR[1] + redR[2] + redR[3];
  }
}

// ---------------------------------------------------------------------------
// Final: loss = (0.625*s1 + srec)/B   (loss_1 == loss_2 forward; 1.25*0.5)
// ---------------------------------------------------------------------------
__global__ __launch_bounds__(256) void final_kernel(
    const float* __restrict__ partial1, const float* __restrict__ partialR,
    float* __restrict__ out) {
  __shared__ float s1s[256], srs[256];
  const int t = threadIdx.x;
  float s1 = 0.f, sr = 0.f;
  for (int i = t; i < 2048; i += 256) s1 += partial1[i];
  for (int i = t; i < 2048; i += 256) sr += partialR[i];
  s1s[t] = s1; srs[t] = sr;
  __syncthreads();
  for (int off = 128; off > 0; off >>= 1) {
    if (t < off) { s1s[t] += s1s[t + off]; srs[t] += srs[t + off]; }
    __syncthreads();
  }
  if (t == 0) out[0] = (0.625f * s1s[0] + srs[0]) * (1.0f / (float)B_SZ);
}

extern "C" void kernel_launch(void* const* d_in, const int* in_sizes, int n_in,
                              void* d_out, int out_size, void* d_ws, size_t ws_size,
                              hipStream_t stream) {
  const float* X     = (const float*)d_in[0];
  const float* W1    = (const float*)d_in[1];
  const float* b1    = (const float*)d_in[2];
  const float* W2    = (const float*)d_in[3];
  const float* b2    = (const float*)d_in[4];
  const float* W3    = (const float*)d_in[5];
  const float* b3    = (const float*)d_in[6];
  const float* W4    = (const float*)d_in[7];
  const float* b4    = (const float*)d_in[8];
  const float* prior = (const float*)d_in[9];

  float* wsf   = (float*)d_ws;
  float* table = wsf;
  float* pn2   = wsf + WS_PN2;
  float* part1 = wsf + WS_P1;
  float* partR = wsf + WS_PR;
  short* W1T   = (short*)(wsf + WS_W1T);
  short* W2T   = (short*)(wsf + WS_W2T);
  short* M2P   = (short*)(wsf + WS_M2P);
  float* out   = (float*)d_out;

  precompute_kernel<<<dim3(K_SZ), dim3(256), 0, stream>>>(W3, b3, W4, b4, prior, table, pn2);
  w1t_kernel<<<dim3(13, 7), dim3(256), 0, stream>>>(W1, W1T);
  prep2_kernel<<<dim3(64), dim3(256), 0, stream>>>(W2, prior, W2T, M2P);
  encoder_kernel<<<dim3(B_SZ / 64), dim3(256), 0, stream>>>(
      X, W1T, b1, W2T, b2, M2P, pn2, table, part1, partR);
  final_kernel<<<dim3(1), dim3(256), 0, stream>>>(part1, partR, out);
}

// Round 5
// 347.951 us; speedup vs baseline: 1.3672x; 1.3672x over previous
//
#include <hip/hip_runtime.h>
#include <hip/hip_bf16.h>

// Problem sizes (fixed)
#define B_SZ 131072
#define F_SZ 784
#define H_SZ 392
#define D_SZ 28
#define K_SZ 512
#define HSTR 424   // hs row stride in shorts (848B: rows spread over banks, ~2-way)

typedef __attribute__((ext_vector_type(8))) short short8v;
typedef __attribute__((ext_vector_type(4))) float f32x4;

__device__ inline short f2bf(float f) {
  __hip_bfloat16 h = __float2bfloat16(f);
  return __builtin_bit_cast(short, h);
}

__device__ inline void glds16(const short* src, short* dst) {
  __builtin_amdgcn_global_load_lds(
      (const __attribute__((address_space(1))) unsigned int*)src,
      (__attribute__((address_space(3))) unsigned int*)dst, 16, 0, 0);
}

__device__ inline int swz4(int r) { return (r & 3) ^ ((r >> 2) & 3); }

// ws layout (float offsets)
#define WS_PN2   401408
#define WS_P1    532992
#define WS_PR    535040
#define WS_W1T   537088
#define WS_W2T   716288
#define WS_M2P   722944

// ---------------------------------------------------------------------------
// Decoder table: x_rec_table[k] = relu(prior[k]@W3+b3)@W4 + b4 ; pn2[k]
// ---------------------------------------------------------------------------
__global__ __launch_bounds__(256) void precompute_kernel(
    const float* __restrict__ W3, const float* __restrict__ b3,
    const float* __restrict__ W4, const float* __restrict__ b4,
    const float* __restrict__ prior,
    float* __restrict__ table, float* __restrict__ pn2) {
  __shared__ float ps[D_SZ];
  __shared__ float h2s[H_SZ];
  const int k = blockIdx.x;
  const int t = threadIdx.x;
  if (t < D_SZ) ps[t] = prior[k * D_SZ + t];
  __syncthreads();
  for (int j = t; j < H_SZ; j += 256) {
    float acc = b3[j];
    #pragma unroll
    for (int d = 0; d < D_SZ; ++d) acc += ps[d] * W3[d * H_SZ + j];
    h2s[j] = fmaxf(acc, 0.f);
  }
  if (t == 0) {
    float s = 0.f;
    #pragma unroll
    for (int d = 0; d < D_SZ; ++d) s += ps[d] * ps[d];
    pn2[k] = s;
  }
  __syncthreads();
  for (int f = t; f < F_SZ; f += 256) {
    float acc = b4[f];
    for (int j = 0; j < H_SZ; ++j) acc += h2s[j] * W4[j * F_SZ + f];
    table[(size_t)k * F_SZ + f] = acc;
  }
}

// ---------------------------------------------------------------------------
// W1T[c][k] = bf16(W1[k][c]), [448][800], zero-padded. LDS-tiled transpose.
// ---------------------------------------------------------------------------
__global__ __launch_bounds__(256) void w1t_kernel(const float* __restrict__ W1,
                                                  short* __restrict__ W1T) {
  __shared__ float tile[64][65];
  const int k0 = blockIdx.x * 64;
  const int c0 = blockIdx.y * 64;
  const int t = threadIdx.x;
  for (int i = t; i < 4096; i += 256) {
    const int kk = i >> 6, cc = i & 63;
    const int k = k0 + kk, c = c0 + cc;
    tile[kk][cc] = (k < F_SZ && c < H_SZ) ? W1[(size_t)k * H_SZ + c] : 0.f;
  }
  __syncthreads();
  for (int i = t; i < 4096; i += 256) {
    const int cc = i >> 6, kk = i & 63;
    const int k = k0 + kk, c = c0 + cc;
    if (k < 800) W1T[(size_t)c * 800 + k] = f2bf(tile[kk][cc]);
  }
}

// ---------------------------------------------------------------------------
// W2T[d][j] = bf16(W2[j][d]) [32][416] ; M2P[c][d] = bf16(-2*prior[c][d]) [512][32]
// ---------------------------------------------------------------------------
__global__ __launch_bounds__(256) void prep2_kernel(
    const float* __restrict__ W2, const float* __restrict__ prior,
    short* __restrict__ W2T, short* __restrict__ M2P) {
  const int i = blockIdx.x * 256 + threadIdx.x;
  if (i < 32 * 416) {
    const int d = i / 416, j = i % 416;
    W2T[i] = f2bf((d < D_SZ && j < H_SZ) ? W2[(size_t)j * D_SZ + d] : 0.f);
  }
  if (i < K_SZ * 32) {
    const int c = i / 32, dd = i % 32;
    M2P[i] = f2bf((dd < D_SZ) ? -2.f * prior[(size_t)c * D_SZ + dd] : 0.f);
  }
}

// ---------------------------------------------------------------------------
// Fused encoder v5: r2-proven LDS-staged loop, 512 threads / 8 waves (2M x 4N)
// so per-wave acc = 2x7 = 56 regs -> 4 waves/SIMD (16 waves/CU, 2 blocks).
//   GEMM1: h = relu(X@W1+b1)  (64 rows x 448 cols per block)
//   Phase 2: z = h@W2+b2 (hs unions over Ws after GEMM1)
//   Phase 3: distances via MFMA (duplicated across wave-halves), argmin
//   loss1 = min distance; fused loss_rec via X re-read (L3-local)
// ---------------------------------------------------------------------------
union WH {
  short Ws[2][448 * 32];  // staged W1T chunk, double-buffered (57,344 B)
  short hs[64][HSTR];     // bf16 h tile (54,272 B)
};

__global__ __launch_bounds__(512, 4) void encoder_kernel(
    const float* __restrict__ X, const short* __restrict__ W1T,
    const float* __restrict__ b1, const short* __restrict__ W2T,
    const float* __restrict__ b2, const short* __restrict__ M2P,
    const float* __restrict__ pn2, const float* __restrict__ table,
    float* __restrict__ partial1, float* __restrict__ partialR) {
  __shared__ WH wh;                 // 57,344 B
  __shared__ short Xs[2][64][32];   // 8,192 B  bf16 X tiles, granule-swizzled
  __shared__ short zs[64][32];      // 4,096 B  bf16 z, granule-swizzled
  __shared__ float pn2s[K_SZ];      // 2,048 B
  __shared__ float zn2p[2][64];     // 512 B
  __shared__ float red1[8], redR[8];

  const int t = threadIdx.x;
  const int w = t >> 6;        // wave 0..7
  const int l = t & 63;
  const int lr = l & 15;
  const int lg = l >> 4;       // 0..3
  const int wm = w >> 2;       // M-half (rows wm*32..)
  const int wn = w & 3;        // N-quarter (cols wn*112..)
  const int row0 = blockIdx.x * 64;

  f32x4 acc[2][7];
  #pragma unroll
  for (int mt = 0; mt < 2; ++mt)
    #pragma unroll
    for (int nt = 0; nt < 7; ++nt) acc[mt][nt] = (f32x4){0.f, 0.f, 0.f, 0.f};

  float b1v[7];
  #pragma unroll
  for (int nt = 0; nt < 7; ++nt) {
    const int c = wn * 112 + nt * 16 + lr;
    b1v[nt] = (c < H_SZ) ? b1[c] : 0.f;
  }
  pn2s[t] = pn2[t];   // 512 threads, one each

  // X staging roles: 512 threads cover 64 rows x 32 cols (4 cols each)
  const int sr = t >> 3;        // staging row 0..63
  const int sg = t & 7;         // col group (4 cols each)
  const int sslot = ((sg >> 1) ^ swz4(sr)) * 8 + (sg & 1) * 4;

  // ---- prologue: stage W(0) + X(0), full drain once ----
  for (int ci = w; ci < 28; ci += 8) {
    const int c = ci * 16 + (l >> 2);
    const int srcg = (l & 3) ^ swz4(c);
    glds16(W1T + (size_t)c * 800 + 8 * srcg, &wh.Ws[0][ci * 512]);
  }
  {
    const float4 xv = *(const float4*)&X[(size_t)(row0 + sr) * F_SZ + sg * 4];
    Xs[0][sr][sslot + 0] = f2bf(xv.x); Xs[0][sr][sslot + 1] = f2bf(xv.y);
    Xs[0][sr][sslot + 2] = f2bf(xv.z); Xs[0][sr][sslot + 3] = f2bf(xv.w);
  }
  __syncthreads();

  // ---- GEMM1 main loop: 25 K-steps of 32, double-buffered (r2 structure) ----
  for (int ks = 0; ks < 25; ++ks) {
    const int cur = ks & 1, nxt = cur ^ 1;
    float4 xv = {0.f, 0.f, 0.f, 0.f};
    if (ks < 24) {
      const int k0n = (ks + 1) * 32;
      for (int ci = w; ci < 28; ci += 8) {
        const int c = ci * 16 + (l >> 2);
        const int srcg = (l & 3) ^ swz4(c);
        glds16(W1T + (size_t)c * 800 + k0n + 8 * srcg, &wh.Ws[nxt][ci * 512]);
      }
      const int kg = k0n + sg * 4;
      if (kg < F_SZ) xv = *(const float4*)&X[(size_t)(row0 + sr) * F_SZ + kg];
    }
    // compute current tile: 2 mt x 7 nt MFMA
    short8v afr[2];
    #pragma unroll
    for (int mt = 0; mt < 2; ++mt) {
      const int row = wm * 32 + mt * 16 + lr;
      const int g2 = lg ^ swz4(row);
      afr[mt] = *(const short8v*)&Xs[cur][row][g2 * 8];
    }
    #pragma unroll
    for (int nt = 0; nt < 7; ++nt) {
      const int c = wn * 112 + nt * 16 + lr;
      const int tg = lg ^ swz4(c);
      const short8v bfr = *(const short8v*)&wh.Ws[cur][c * 32 + tg * 8];
      #pragma unroll
      for (int mt = 0; mt < 2; ++mt)
        acc[mt][nt] = __builtin_amdgcn_mfma_f32_16x16x32_bf16(afr[mt], bfr, acc[mt][nt], 0, 0, 0);
    }
    if (ks < 24) {
      Xs[nxt][sr][sslot + 0] = f2bf(xv.x); Xs[nxt][sr][sslot + 1] = f2bf(xv.y);
      Xs[nxt][sr][sslot + 2] = f2bf(xv.z); Xs[nxt][sr][sslot + 3] = f2bf(xv.w);
    }
    __syncthreads();
  }

  // ---- bias+relu, write h tile (bf16) into hs (unions over Ws) ----
  #pragma unroll
  for (int nt = 0; nt < 7; ++nt) {
    const int c = wn * 112 + nt * 16 + lr;
    if (c < 416) {
      #pragma unroll
      for (int mt = 0; mt < 2; ++mt)
        #pragma unroll
        for (int rg = 0; rg < 4; ++rg) {
          const int row = wm * 32 + mt * 16 + 4 * lg + rg;
          wh.hs[row][c] = f2bf(fmaxf(acc[mt][nt][rg] + b1v[nt], 0.f));
        }
    }
  }
  __syncthreads();

  // ---- phase 2: z = h@W2 + b2 (8 waves: rowgrp w>>1, d-half w&1) ----
  {
    const int rL = (w >> 1) * 16 + lr;
    const int cD = (w & 1) * 16 + lr;
    const float b2v = (cD < D_SZ) ? b2[cD] : 0.f;
    f32x4 za = (f32x4){b2v, b2v, b2v, b2v};
    #pragma unroll
    for (int ks2 = 0; ks2 < 13; ++ks2) {
      const int u = 4 * ks2 + lg;
      const short8v af = *(const short8v*)&wh.hs[rL][u * 8];
      const short8v bf = *(const short8v*)&W2T[cD * 416 + ks2 * 32 + lg * 8];
      za = __builtin_amdgcn_mfma_f32_16x16x32_bf16(af, bf, za, 0, 0, 0);
    }
    #pragma unroll
    for (int rg = 0; rg < 4; ++rg) {
      float s = za[rg] * za[rg];
      s += __shfl_xor(s, 1); s += __shfl_xor(s, 2);
      s += __shfl_xor(s, 4); s += __shfl_xor(s, 8);
      const int row = (w >> 1) * 16 + 4 * lg + rg;
      if (lr == 0) zn2p[w & 1][row] = s;
      const int zg = (cD >> 3) ^ swz4(row);
      zs[row][zg * 8 + (cD & 7)] = f2bf(za[rg]);
    }
  }
  __syncthreads();

  // ---- phase 3: d = ||z||^2 - 2 z.p + ||p||^2 via MFMA, argmin ----
  // wave-halves w and w+4 duplicate rowgroup (w&3) to avoid cross-wave sync
  const int rowA = (w & 3) * 16 + lr;
  const int gA = lg ^ swz4(rowA);
  const short8v zf = *(const short8v*)&zs[rowA][gA * 8];
  float zn2r[4];
  #pragma unroll
  for (int rg = 0; rg < 4; ++rg) {
    const int row = (w & 3) * 16 + 4 * lg + rg;
    zn2r[rg] = zn2p[0][row] + zn2p[1][row];
  }
  float bv[4] = {3.4e38f, 3.4e38f, 3.4e38f, 3.4e38f};
  int bi[4] = {0, 0, 0, 0};
  #pragma unroll 8
  for (int nt = 0; nt < 32; ++nt) {
    const int code = nt * 16 + lr;
    const short8v pf = *(const short8v*)&M2P[code * 32 + lg * 8];
    f32x4 dacc = (f32x4){zn2r[0], zn2r[1], zn2r[2], zn2r[3]};
    dacc = __builtin_amdgcn_mfma_f32_16x16x32_bf16(zf, pf, dacc, 0, 0, 0);
    const float pn = pn2s[code];
    #pragma unroll
    for (int rg = 0; rg < 4; ++rg) {
      const float dv = fmaxf(dacc[rg] + pn, 0.f);
      if (dv < bv[rg]) { bv[rg] = dv; bi[rg] = code; }  // ascending: first-min
    }
  }
  #pragma unroll
  for (int rg = 0; rg < 4; ++rg) {
    float v = bv[rg]; int ii = bi[rg];
    #pragma unroll
    for (int m = 1; m <= 8; m <<= 1) {
      const float ov = __shfl_xor(v, m);
      const int oi = __shfl_xor(ii, m);
      if (ov < v || (ov == v && oi < ii)) { v = ov; ii = oi; }
    }
    bv[rg] = v; bi[rg] = ii;
  }

  // loss_1 partial: min distance itself; only waves 0-3 contribute (dup halves)
  float lsum = (w < 4 && lr == 0) ? (bv[0] + bv[1] + bv[2] + bv[3]) : 0.f;

  // ---- fused loss_rec: wave handles 8 rows of its 16-row group ----
  float racc = 0.f;
  #pragma unroll 2
  for (int rr = 0; rr < 8; ++rr) {
    const int roff = (w >> 2) * 8 + rr;            // row offset in group 0..15
    const int kk = __shfl(bi[roff & 3], (roff >> 2) << 4);
    const int grow = row0 + (w & 3) * 16 + roff;
    const float4* xr4 = (const float4*)&X[(size_t)grow * F_SZ];
    const float4* tr4 = (const float4*)&table[(size_t)kk * F_SZ];
    #pragma unroll
    for (int s = 0; s < 3; ++s) {
      const int i = l + 64 * s;
      const float4 xv = xr4[i], tv = tr4[i];
      const float d0 = xv.x - tv.x, d1 = xv.y - tv.y, d2 = xv.z - tv.z, d3 = xv.w - tv.w;
      racc += d0 * d0 + d1 * d1 + d2 * d2 + d3 * d3;
    }
    if (l < 4) {
      const int i = 192 + l;
      const float4 xv = xr4[i], tv = tr4[i];
      const float d0 = xv.x - tv.x, d1 = xv.y - tv.y, d2 = xv.z - tv.z, d3 = xv.w - tv.w;
      racc += d0 * d0 + d1 * d1 + d2 * d2 + d3 * d3;
    }
  }

  // ---- block reduction ----
  #pragma unroll
  for (int m = 1; m <= 32; m <<= 1) {
    lsum += __shfl_xor(lsum, m);
    racc += __shfl_xor(racc, m);
  }
  if (l == 0) { red1[w] = lsum; redR[w] = racc; }
  __syncthreads();
  if (t == 0) {
    float s1 = 0.f, sr2 = 0.f;
    #pragma unroll
    for (int i = 0; i < 8; ++i) { s1 += red1[i]; sr2 += redR[i]; }
    partial1[blockIdx.x] = s1;
    partialR[blockIdx.x] = sr2;
  }
}

// ---------------------------------------------------------------------------
// Final: loss = (0.625*s1 + srec)/B   (loss_1 == loss_2 forward; 1.25*0.5)
// ---------------------------------------------------------------------------
__global__ __launch_bounds__(256) void final_kernel(
    const float* __restrict__ partial1, const float* __restrict__ partialR,
    float* __restrict__ out) {
  __shared__ float s1s[256], srs[256];
  const int t = threadIdx.x;
  float s1 = 0.f, sr = 0.f;
  for (int i = t; i < 2048; i += 256) s1 += partial1[i];
  for (int i = t; i < 2048; i += 256) sr += partialR[i];
  s1s[t] = s1; srs[t] = sr;
  __syncthreads();
  for (int off = 128; off > 0; off >>= 1) {
    if (t < off) { s1s[t] += s1s[t + off]; srs[t] += srs[t + off]; }
    __syncthreads();
  }
  if (t == 0) out[0] = (0.625f * s1s[0] + srs[0]) * (1.0f / (float)B_SZ);
}

extern "C" void kernel_launch(void* const* d_in, const int* in_sizes, int n_in,
                              void* d_out, int out_size, void* d_ws, size_t ws_size,
                              hipStream_t stream) {
  const float* X     = (const float*)d_in[0];
  const float* W1    = (const float*)d_in[1];
  const float* b1    = (const float*)d_in[2];
  const float* W2    = (const float*)d_in[3];
  const float* b2    = (const float*)d_in[4];
  const float* W3    = (const float*)d_in[5];
  const float* b3    = (const float*)d_in[6];
  const float* W4    = (const float*)d_in[7];
  const float* b4    = (const float*)d_in[8];
  const float* prior = (const float*)d_in[9];

  float* wsf   = (float*)d_ws;
  float* table = wsf;
  float* pn2   = wsf + WS_PN2;
  float* part1 = wsf + WS_P1;
  float* partR = wsf + WS_PR;
  short* W1T   = (short*)(wsf + WS_W1T);
  short* W2T   = (short*)(wsf + WS_W2T);
  short* M2P   = (short*)(wsf + WS_M2P);
  float* out   = (float*)d_out;

  precompute_kernel<<<dim3(K_SZ), dim3(256), 0, stream>>>(W3, b3, W4, b4, prior, table, pn2);
  w1t_kernel<<<dim3(13, 7), dim3(256), 0, stream>>>(W1, W1T);
  prep2_kernel<<<dim3(64), dim3(256), 0, stream>>>(W2, prior, W2T, M2P);
  encoder_kernel<<<dim3(B_SZ / 64), dim3(512), 0, stream>>>(
      X, W1T, b1, W2T, b2, M2P, pn2, table, part1, partR);
  final_kernel<<<dim3(1), dim3(256), 0, stream>>>(part1, partR, out);
}